// Round 1
// baseline (256.977 us; speedup 1.0000x reference)
//
#include <hip/hip_runtime.h>

// Rasterize_52321291600271
// B=4, NV=1024, NF=1024, RASTER S=256, output 4x128x128 float32.
//
// Coverage(b, subpixel p) = OR over 1024 faces of
//   [all 3 fwd crosses > 0] OR [all 3 rev crosses > 0]
// with crosses computed bit-exactly as the reference does (IEEE f32
// mul/mul/sub, no FMA). Then vertical flip + 2x2 mean -> 128x128.

constexpr int S      = 256;   // RASTER
constexpr int NVERT  = 1024;
constexpr int NFACE  = 1024;
constexpr int OUTSZ  = 128;   // output image side
constexpr int CHUNKF = 256;   // faces staged per LDS chunk

__global__ __launch_bounds__(256)
void raster_cov_kernel(const float* __restrict__ verts,
                       const int*   __restrict__ faces,
                       float*       __restrict__ out)
{
    // per-face: [0]=(xa,ya,xb,yb) [1]=(xc,yc,exab,eyab) [2]=(exbc,eybc,exca,eyca)
    __shared__ float4 fd[CHUNKF][3];

    const int b   = blockIdx.z;
    const int tid = threadIdx.x;
    const int tx  = tid & 15;
    const int ty  = tid >> 4;
    const int sx  = (blockIdx.x << 4) + tx;   // subpixel col  -> px
    const int sy  = (blockIdx.y << 4) + ty;   // subpixel row  -> py

    // c[j] = (2j+1-S)/S : odd/256 -> exactly representable; mul by 2^-8 exact.
    const float px = (float)(2 * sx + 1 - S) * (1.0f / (float)S);
    const float py = (float)(2 * sy + 1 - S) * (1.0f / (float)S);

    const float* __restrict__ vb = verts + (size_t)b * NVERT * 2;
    const int*   __restrict__ fb = faces + (size_t)b * NFACE * 3;

    bool covered = false;

    for (int c0 = 0; c0 < NFACE; c0 += CHUNKF) {
        // ---- stage one chunk of gathered face data into LDS ----
        {
            const int f  = c0 + tid;            // CHUNKF == blockDim.x
            const int i0 = fb[f * 3 + 0];
            const int i1 = fb[f * 3 + 1];
            const int i2 = fb[f * 3 + 2];
            const float xa = vb[i0 * 2 + 0], ya = vb[i0 * 2 + 1];
            const float xb = vb[i1 * 2 + 0], yb = vb[i1 * 2 + 1];
            const float xc = vb[i2 * 2 + 0], yc = vb[i2 * 2 + 1];
            fd[tid][0] = make_float4(xa, ya, xb, yb);
            fd[tid][1] = make_float4(xc, yc, __fsub_rn(xb, xa), __fsub_rn(yb, ya));
            fd[tid][2] = make_float4(__fsub_rn(xc, xb), __fsub_rn(yc, yb),
                                     __fsub_rn(xa, xc), __fsub_rn(ya, yc));
        }
        __syncthreads();

        for (int f = 0; f < CHUNKF; ++f) {
            if (__all((int)covered)) break;     // wave-level early exit
            if (!covered) {
                const float4 A  = fd[f][0];
                const float4 Bv = fd[f][1];
                const float4 C  = fd[f][2];
                const float dxa = __fsub_rn(px, A.x),  dya = __fsub_rn(py, A.y);
                const float dxb = __fsub_rn(px, A.z),  dyb = __fsub_rn(py, A.w);
                const float dxc = __fsub_rn(px, Bv.x), dyc = __fsub_rn(py, Bv.y);
                const float exab = Bv.z, eyab = Bv.w;
                const float exbc = C.x,  eybc = C.y;
                const float exca = C.z,  eyca = C.w;
                // forward winding (a,b,c): edges a->b@a, b->c@b, c->a@c
                const float F0 = __fsub_rn(__fmul_rn(exab, dya), __fmul_rn(eyab, dxa));
                const float F1 = __fsub_rn(__fmul_rn(exbc, dyb), __fmul_rn(eybc, dxb));
                const float F2 = __fsub_rn(__fmul_rn(exca, dyc), __fmul_rn(eyca, dxc));
                // reversed winding (c,b,a): edges c->b@c, b->a@b, a->c@a
                // fl((-e)*d) == -fl(e*d) and fl(-u+v) == fl(v-u): bit-exact.
                const float R0 = __fsub_rn(__fmul_rn(eybc, dxc), __fmul_rn(exbc, dyc));
                const float R1 = __fsub_rn(__fmul_rn(eyab, dxb), __fmul_rn(exab, dyb));
                const float R2 = __fsub_rn(__fmul_rn(eyca, dxa), __fmul_rn(exca, dya));
                const bool fwd = (F0 > 0.0f) & (F1 > 0.0f) & (F2 > 0.0f);
                const bool rev = (R0 > 0.0f) & (R1 > 0.0f) & (R2 > 0.0f);
                covered = covered || fwd || rev;
            }
        }

        // barrier (protects fd for next staging) + block-level early exit
        if (__syncthreads_and((int)covered)) break;
    }

    // ---- vertical flip + 2x2 mean, fused via intra-wave shuffles ----
    // 2x2 subpixel group = lanes {t, t^1, t^16, t^17} (tx bit0, ty bit0).
    float c = covered ? 1.0f : 0.0f;
    c += __shfl_xor(c, 1);
    c += __shfl_xor(c, 16);
    if (((tx & 1) == 0) && ((ty & 1) == 0)) {
        const int X = sx >> 1;
        const int Y = (OUTSZ - 1) - (sy >> 1);   // vertical flip
        out[((size_t)b * OUTSZ + Y) * OUTSZ + X] = c * 0.25f;
    }
}

extern "C" void kernel_launch(void* const* d_in, const int* in_sizes, int n_in,
                              void* d_out, int out_size, void* d_ws, size_t ws_size,
                              hipStream_t stream) {
    const float* verts = (const float*)d_in[0];
    const int*   faces = (const int*)d_in[1];
    float*       out   = (float*)d_out;

    const int B = in_sizes[0] / (NVERT * 2);   // = 4
    dim3 grid(S / 16, S / 16, B);
    raster_cov_kernel<<<grid, dim3(256), 0, stream>>>(verts, faces, out);
}

// Round 3
// 47.144 us; speedup vs baseline: 5.4509x; 5.4509x over previous
//
#include <hip/hip_runtime.h>

// Rasterize_52321291600271 — round 3 (round 2 + signed tile-rect fix)
// B=4, NV=1024, NF=1024, RASTER S=256, output 4x128x128 float32.
//
// Kernel 1 (face_setup): per original face, gather vertices, precompute
//   bbox (xmin,ymin,xmax,ymax) and 3 float4 records:
//   [0]=(xa,ya,xb,yb) [1]=(xc,yc,exab,eyab) [2]=(exbc,eybc,exca,eyca)
// Kernel 2 (raster8): one wave per 8x8-subpixel tile; per 64-face chunk,
//   coalesced bbox load + tile-rect overlap ballot; exact 6-cross test
//   (bit-identical to reference: IEEE f32 mul/mul/sub, no FMA) only on
//   ballot bits; wave-level early exit when all 64 subpixels covered.
//   Fused vertical flip + 2x2 mean via intra-wave shuffles.

constexpr int S     = 256;    // RASTER
constexpr int NVERT = 1024;
constexpr int NFACE = 1024;
constexpr int OUTSZ = 128;

__global__ __launch_bounds__(256)
void face_setup(const float* __restrict__ verts, const int* __restrict__ faces,
                float4* __restrict__ bbox, float4* __restrict__ recs, int total)
{
    const int g = blockIdx.x * 256 + threadIdx.x;   // global face id (b*NFACE+f)
    if (g >= total) return;
    const int b = g >> 10;                          // / NFACE
    const float* __restrict__ vb = verts + (size_t)b * NVERT * 2;
    const int*   __restrict__ fp = faces + (size_t)g * 3;
    const int i0 = fp[0], i1 = fp[1], i2 = fp[2];
    const float xa = vb[i0 * 2 + 0], ya = vb[i0 * 2 + 1];
    const float xb = vb[i1 * 2 + 0], yb = vb[i1 * 2 + 1];
    const float xc = vb[i2 * 2 + 0], yc = vb[i2 * 2 + 1];
    bbox[g] = make_float4(fminf(xa, fminf(xb, xc)), fminf(ya, fminf(yb, yc)),
                          fmaxf(xa, fmaxf(xb, xc)), fmaxf(ya, fmaxf(yb, yc)));
    recs[3 * (size_t)g + 0] = make_float4(xa, ya, xb, yb);
    recs[3 * (size_t)g + 1] = make_float4(xc, yc, __fsub_rn(xb, xa), __fsub_rn(yb, ya));
    recs[3 * (size_t)g + 2] = make_float4(__fsub_rn(xc, xb), __fsub_rn(yc, yb),
                                          __fsub_rn(xa, xc), __fsub_rn(ya, yc));
}

__global__ __launch_bounds__(64)
void raster8(const float4* __restrict__ bbox, const float4* __restrict__ recs,
             float* __restrict__ out)
{
    const int b   = blockIdx.z;
    const int tid = threadIdx.x;
    const int tx  = tid & 7;
    const int ty  = tid >> 3;
    const int bx  = (int)(blockIdx.x << 3);   // SIGNED tile origin (bugfix:
    const int by  = (int)(blockIdx.y << 3);   // unsigned wrap made rect huge)
    const int sx  = bx + tx;
    const int sy  = by + ty;

    // (2j+1-S)/S : odd/256 exactly representable; *2^-8 exact.
    const float px = (float)(2 * sx + 1 - S) * (1.0f / (float)S);
    const float py = (float)(2 * sy + 1 - S) * (1.0f / (float)S);
    // tile's pixel-center rect (for conservative bbox culling)
    const float rx0 = (float)(2 * bx + 1 - S)       * (1.0f / (float)S);
    const float rx1 = (float)(2 * (bx + 7) + 1 - S) * (1.0f / (float)S);
    const float ry0 = (float)(2 * by + 1 - S)       * (1.0f / (float)S);
    const float ry1 = (float)(2 * (by + 7) + 1 - S) * (1.0f / (float)S);

    const float4* __restrict__ bb = bbox + (size_t)b * NFACE;
    const float4* __restrict__ rb = recs + (size_t)b * NFACE * 3;

    bool covered = false;

    for (int c0 = 0; c0 < NFACE; c0 += 64) {
        const float4 box = bb[c0 + tid];            // coalesced, L2-resident
        const bool ov = (box.x <= rx1) & (box.z >= rx0) &
                        (box.y <= ry1) & (box.w >= ry0);
        unsigned long long m = __ballot((int)ov);   // wave-uniform mask
        while (m) {
            const int f = __ffsll(m) - 1;
            m &= m - 1;
            const float4* __restrict__ r = rb + 3 * (size_t)(c0 + f);
            const float4 A  = r[0];                 // wave-uniform -> s_load
            const float4 Bv = r[1];
            const float4 C  = r[2];
            const float dxa = __fsub_rn(px, A.x),  dya = __fsub_rn(py, A.y);
            const float dxb = __fsub_rn(px, A.z),  dyb = __fsub_rn(py, A.w);
            const float dxc = __fsub_rn(px, Bv.x), dyc = __fsub_rn(py, Bv.y);
            const float exab = Bv.z, eyab = Bv.w;
            const float exbc = C.x,  eybc = C.y;
            const float exca = C.z,  eyca = C.w;
            // forward winding (a,b,c)
            const float F0 = __fsub_rn(__fmul_rn(exab, dya), __fmul_rn(eyab, dxa));
            const float F1 = __fsub_rn(__fmul_rn(exbc, dyb), __fmul_rn(eybc, dxb));
            const float F2 = __fsub_rn(__fmul_rn(exca, dyc), __fmul_rn(eyca, dxc));
            // reversed winding (c,b,a): exact negations of the fwd edge vecs
            const float R0 = __fsub_rn(__fmul_rn(eybc, dxc), __fmul_rn(exbc, dyc));
            const float R1 = __fsub_rn(__fmul_rn(eyab, dxb), __fmul_rn(exab, dyb));
            const float R2 = __fsub_rn(__fmul_rn(eyca, dxa), __fmul_rn(exca, dya));
            const bool fwd = (F0 > 0.0f) & (F1 > 0.0f) & (F2 > 0.0f);
            const bool rev = (R0 > 0.0f) & (R1 > 0.0f) & (R2 > 0.0f);
            covered = covered || fwd || rev;
            if (__all((int)covered)) { m = 0; }     // wave fully covered
        }
        if (__all((int)covered)) break;
    }

    // vertical flip + 2x2 mean: quad lanes {t, t^1, t^8, t^9}
    float c = covered ? 1.0f : 0.0f;
    c += __shfl_xor(c, 1);
    c += __shfl_xor(c, 8);
    if (((tx & 1) == 0) && ((ty & 1) == 0)) {
        const int X = sx >> 1;
        const int Y = (OUTSZ - 1) - (sy >> 1);      // vertical flip
        out[((size_t)b * OUTSZ + Y) * OUTSZ + X] = c * 0.25f;
    }
}

extern "C" void kernel_launch(void* const* d_in, const int* in_sizes, int n_in,
                              void* d_out, int out_size, void* d_ws, size_t ws_size,
                              hipStream_t stream) {
    const float* verts = (const float*)d_in[0];
    const int*   faces = (const int*)d_in[1];
    float*       out   = (float*)d_out;

    const int B     = in_sizes[0] / (NVERT * 2);    // = 4
    const int total = B * NFACE;

    float4* ws4  = (float4*)d_ws;
    float4* bbox = ws4;                              // [B*NFACE]
    float4* recs = ws4 + total;                      // [B*NFACE][3]

    face_setup<<<(total + 255) / 256, 256, 0, stream>>>(verts, faces, bbox, recs, total);

    dim3 grid(S / 8, S / 8, B);
    raster8<<<grid, dim3(64), 0, stream>>>(bbox, recs, out);
}

// Round 4
// 24.705 us; speedup vs baseline: 10.4018x; 1.9083x over previous
//
#include <hip/hip_runtime.h>

// Rasterize_52321291600271 — round 4
// B=4, NV=1024, NF=1024, RASTER S=256, output 4x128x128 float32.
//
// face_setup: per face, gather vertices -> 3 float4 records:
//   [0]=(xa,ya,xb,yb) [1]=(xc,yc,exab,eyab) [2]=(exbc,eybc,exca,eyca)
// raster8: one wave per 8x8-subpixel tile. Per 64-face chunk:
//   - lane i loads face (c0+i)'s records (coalesced 48B/lane)
//   - per-lane conservative EDGE cull vs tile rect (affine cross ->
//     extrema at rect corners; margin 1e-4 >> 2e-6 FP error)
//   - ballot + LDS compaction of surviving records
//   - serial exact 6-cross test over compacted LDS (bit-identical math:
//     IEEE f32 mul/mul/sub via __fmul_rn/__fsub_rn, no FMA)
//   - wave early-exit when all 64 subpixels covered
// Fused vertical flip + 2x2 mean via intra-wave shuffles.

constexpr int S     = 256;
constexpr int NVERT = 1024;
constexpr int NFACE = 1024;
constexpr int OUTSZ = 128;

__global__ __launch_bounds__(256)
void face_setup(const float* __restrict__ verts, const int* __restrict__ faces,
                float4* __restrict__ recs, int total)
{
    const int g = blockIdx.x * 256 + threadIdx.x;   // b*NFACE + f
    if (g >= total) return;
    const int b = g >> 10;
    const float* __restrict__ vb = verts + (size_t)b * NVERT * 2;
    const int*   __restrict__ fp = faces + (size_t)g * 3;
    const int i0 = fp[0], i1 = fp[1], i2 = fp[2];
    const float xa = vb[i0 * 2 + 0], ya = vb[i0 * 2 + 1];
    const float xb = vb[i1 * 2 + 0], yb = vb[i1 * 2 + 1];
    const float xc = vb[i2 * 2 + 0], yc = vb[i2 * 2 + 1];
    recs[3 * (size_t)g + 0] = make_float4(xa, ya, xb, yb);
    recs[3 * (size_t)g + 1] = make_float4(xc, yc, __fsub_rn(xb, xa), __fsub_rn(yb, ya));
    recs[3 * (size_t)g + 2] = make_float4(__fsub_rn(xc, xb), __fsub_rn(yc, yb),
                                          __fsub_rn(xa, xc), __fsub_rn(ya, yc));
}

__global__ __launch_bounds__(64)
void raster8(const float4* __restrict__ recs, float* __restrict__ out)
{
    __shared__ float4 fd[64][3];

    const int b   = blockIdx.z;
    const int tid = threadIdx.x;
    const int tx  = tid & 7;
    const int ty  = tid >> 3;
    const int bx  = (int)(blockIdx.x << 3);   // signed tile origin
    const int by  = (int)(blockIdx.y << 3);
    const int sx  = bx + tx;
    const int sy  = by + ty;

    // (2j+1-S)/S exactly representable
    const float px = (float)(2 * sx + 1 - S) * (1.0f / (float)S);
    const float py = (float)(2 * sy + 1 - S) * (1.0f / (float)S);
    const float rx0 = (float)(2 * bx + 1 - S)       * (1.0f / (float)S);
    const float rx1 = (float)(2 * (bx + 7) + 1 - S) * (1.0f / (float)S);
    const float ry0 = (float)(2 * by + 1 - S)       * (1.0f / (float)S);
    const float ry1 = (float)(2 * (by + 7) + 1 - S) * (1.0f / (float)S);
    constexpr float MARGIN = 1e-4f;

    const float4* __restrict__ rb = recs + (size_t)b * NFACE * 3;

    bool covered = false;

    for (int c0 = 0; c0 < NFACE; c0 += 64) {
        // ---- per-lane load + conservative edge cull of face (c0+tid) ----
        const float4 r0 = rb[3 * (size_t)(c0 + tid) + 0];
        const float4 r1 = rb[3 * (size_t)(c0 + tid) + 1];
        const float4 r2 = rb[3 * (size_t)(c0 + tid) + 2];
        bool keep;
        {
            const float xa = r0.x, ya = r0.y, xb = r0.z, yb = r0.w;
            const float xc = r1.x, yc = r1.y;
            const float exab = r1.z, eyab = r1.w;
            const float exbc = r2.x, eybc = r2.y;
            const float exca = r2.z, eyca = r2.w;
            // F(p) = ex*(py-vy) - ey*(px-vx); extrema over rect at corners.
            #define EDGE_EXT(ex, ey, vx, vy, mx, mn)                          \
                {                                                             \
                    const float syp = (ex > 0.0f) ? ry1 : ry0;                \
                    const float syn = (ex > 0.0f) ? ry0 : ry1;                \
                    const float sxp = (ey > 0.0f) ? rx0 : rx1;                \
                    const float sxn = (ey > 0.0f) ? rx1 : rx0;                \
                    mx = (ex) * (syp - (vy)) - (ey) * (sxp - (vx));           \
                    mn = (ex) * (syn - (vy)) - (ey) * (sxn - (vx));           \
                }
            float mxAB, mnAB, mxBC, mnBC, mxCA, mnCA;
            EDGE_EXT(exab, eyab, xa, ya, mxAB, mnAB)
            EDGE_EXT(exbc, eybc, xb, yb, mxBC, mnBC)
            EDGE_EXT(exca, eyca, xc, yc, mxCA, mnCA)
            #undef EDGE_EXT
            const bool fwdPossible = (mxAB > -MARGIN) & (mxBC > -MARGIN) & (mxCA > -MARGIN);
            const bool revPossible = (mnAB <  MARGIN) & (mnBC <  MARGIN) & (mnCA <  MARGIN);
            keep = fwdPossible | revPossible;
        }

        // ---- ballot + LDS compaction ----
        const unsigned long long m = __ballot((int)keep);
        const int cnt = __popcll(m);
        if (keep) {
            const int slot = __popcll(m & ((1ull << tid) - 1));
            fd[slot][0] = r0;
            fd[slot][1] = r1;
            fd[slot][2] = r2;
        }
        __syncthreads();

        // ---- serial exact test over compacted survivors (LDS broadcast) ----
        for (int i = 0; i < cnt; ++i) {
            const float4 A  = fd[i][0];
            const float4 Bv = fd[i][1];
            const float4 C  = fd[i][2];
            const float dxa = __fsub_rn(px, A.x),  dya = __fsub_rn(py, A.y);
            const float dxb = __fsub_rn(px, A.z),  dyb = __fsub_rn(py, A.w);
            const float dxc = __fsub_rn(px, Bv.x), dyc = __fsub_rn(py, Bv.y);
            const float exab = Bv.z, eyab = Bv.w;
            const float exbc = C.x,  eybc = C.y;
            const float exca = C.z,  eyca = C.w;
            const float F0 = __fsub_rn(__fmul_rn(exab, dya), __fmul_rn(eyab, dxa));
            const float F1 = __fsub_rn(__fmul_rn(exbc, dyb), __fmul_rn(eybc, dxb));
            const float F2 = __fsub_rn(__fmul_rn(exca, dyc), __fmul_rn(eyca, dxc));
            const float R0 = __fsub_rn(__fmul_rn(eybc, dxc), __fmul_rn(exbc, dyc));
            const float R1 = __fsub_rn(__fmul_rn(eyab, dxb), __fmul_rn(exab, dyb));
            const float R2 = __fsub_rn(__fmul_rn(eyca, dxa), __fmul_rn(exca, dya));
            const bool fwd = (F0 > 0.0f) & (F1 > 0.0f) & (F2 > 0.0f);
            const bool rev = (R0 > 0.0f) & (R1 > 0.0f) & (R2 > 0.0f);
            covered = covered || fwd || rev;
            if (__all((int)covered)) break;
        }

        const bool done = __all((int)covered);   // wave-uniform
        __syncthreads();                          // protect fd for next chunk
        if (done) break;
    }

    // vertical flip + 2x2 mean: quad lanes {t, t^1, t^8, t^9}
    float c = covered ? 1.0f : 0.0f;
    c += __shfl_xor(c, 1);
    c += __shfl_xor(c, 8);
    if (((tx & 1) == 0) && ((ty & 1) == 0)) {
        const int X = sx >> 1;
        const int Y = (OUTSZ - 1) - (sy >> 1);   // vertical flip
        out[((size_t)b * OUTSZ + Y) * OUTSZ + X] = c * 0.25f;
    }
}

extern "C" void kernel_launch(void* const* d_in, const int* in_sizes, int n_in,
                              void* d_out, int out_size, void* d_ws, size_t ws_size,
                              hipStream_t stream) {
    const float* verts = (const float*)d_in[0];
    const int*   faces = (const int*)d_in[1];
    float*       out   = (float*)d_out;

    const int B     = in_sizes[0] / (NVERT * 2);   // = 4
    const int total = B * NFACE;

    float4* recs = (float4*)d_ws;                  // [B*NFACE][3]

    face_setup<<<(total + 255) / 256, 256, 0, stream>>>(verts, faces, recs, total);

    dim3 grid(S / 8, S / 8, B);
    raster8<<<grid, dim3(64), 0, stream>>>(recs, out);
}

// Round 5
// 24.058 us; speedup vs baseline: 10.6816x; 1.0269x over previous
//
#include <hip/hip_runtime.h>

// Rasterize_52321291600271 — round 5
// B=4, NV=1024, NF=1024, RASTER S=256, output 4x128x128 float32.
//
// face_setup: per face, gather vertices -> 3 float4 record planes (SoA):
//   P0=(xa,ya,xb,yb) P1=(xc,yc,exab,eyab) P2=(exbc,eybc,exca,eyca)
// raster8: one wave per 8x8-subpixel tile. Per 64-face chunk:
//   - register double-buffer: prefetch next chunk while testing current
//   - per-lane conservative FULL-SAT cull (3 edge axes via center+radius
//     + rect axes via inline bbox min3/max3; MARGIN 1e-4 >> ~1e-6 FP err)
//   - ballot + LDS compaction of surviving records
//   - serial exact 6-cross test over compacted LDS (bit-identical to the
//     reference: IEEE f32 mul/mul/sub via __fmul_rn/__fsub_rn, no FMA)
//   - wave early-exit when all 64 subpixels covered
// Fused vertical flip + 2x2 mean via intra-wave shuffles.

constexpr int S     = 256;
constexpr int NVERT = 1024;
constexpr int NFACE = 1024;
constexpr int OUTSZ = 128;

__global__ __launch_bounds__(256)
void face_setup(const float* __restrict__ verts, const int* __restrict__ faces,
                float4* __restrict__ recs, int total)
{
    const int g = blockIdx.x * 256 + threadIdx.x;   // b*NFACE + f
    if (g >= total) return;
    const int b = g >> 10;
    const float* __restrict__ vb = verts + (size_t)b * NVERT * 2;
    const int*   __restrict__ fp = faces + (size_t)g * 3;
    const int i0 = fp[0], i1 = fp[1], i2 = fp[2];
    const float xa = vb[i0 * 2 + 0], ya = vb[i0 * 2 + 1];
    const float xb = vb[i1 * 2 + 0], yb = vb[i1 * 2 + 1];
    const float xc = vb[i2 * 2 + 0], yc = vb[i2 * 2 + 1];
    recs[0 * total + g] = make_float4(xa, ya, xb, yb);
    recs[1 * total + g] = make_float4(xc, yc, __fsub_rn(xb, xa), __fsub_rn(yb, ya));
    recs[2 * total + g] = make_float4(__fsub_rn(xc, xb), __fsub_rn(yc, yb),
                                      __fsub_rn(xa, xc), __fsub_rn(ya, yc));
}

__global__ __launch_bounds__(64)
void raster8(const float4* __restrict__ recs, float* __restrict__ out, int total)
{
    __shared__ float4 fd[64][3];

    const int b   = blockIdx.z;
    const int tid = threadIdx.x;
    const int tx  = tid & 7;
    const int ty  = tid >> 3;
    const int bx  = (int)(blockIdx.x << 3);   // signed tile origin
    const int by  = (int)(blockIdx.y << 3);
    const int sx  = bx + tx;
    const int sy  = by + ty;

    // (2j+1-S)/S exactly representable
    const float px = (float)(2 * sx + 1 - S) * (1.0f / (float)S);
    const float py = (float)(2 * sy + 1 - S) * (1.0f / (float)S);
    const float rx0 = (float)(2 * bx + 1 - S)       * (1.0f / (float)S);
    const float rx1 = (float)(2 * (bx + 7) + 1 - S) * (1.0f / (float)S);
    const float ry0 = (float)(2 * by + 1 - S)       * (1.0f / (float)S);
    const float ry1 = (float)(2 * (by + 7) + 1 - S) * (1.0f / (float)S);
    constexpr float MARGIN = 1e-4f;
    const float cx = (rx0 + rx1) * 0.5f;
    const float cy = (ry0 + ry1) * 0.5f;
    const float h  = (rx1 - rx0) * 0.5f;      // uniform half-extent
    const float rx0m = rx0 - MARGIN, rx1m = rx1 + MARGIN;
    const float ry0m = ry0 - MARGIN, ry1m = ry1 + MARGIN;

    const float4* __restrict__ P0 = recs + 0 * (size_t)total + (size_t)b * NFACE;
    const float4* __restrict__ P1 = recs + 1 * (size_t)total + (size_t)b * NFACE;
    const float4* __restrict__ P2 = recs + 2 * (size_t)total + (size_t)b * NFACE;

    bool covered = false;

    // prime chunk 0
    float4 r0 = P0[tid], r1 = P1[tid], r2 = P2[tid];

    for (int c0 = 0; c0 < NFACE; c0 += 64) {
        // ---- prefetch next chunk (wraps at end; result unused then) ----
        const int nidx = ((c0 + 64) & (NFACE - 1)) + tid;
        const float4 n0 = P0[nidx];
        const float4 n1 = P1[nidx];
        const float4 n2 = P2[nidx];

        // ---- per-lane conservative full-SAT cull of face (c0+tid) ----
        bool keep;
        {
            const float xa = r0.x, ya = r0.y, xb = r0.z, yb = r0.w;
            const float xc = r1.x, yc = r1.y;
            const float exab = r1.z, eyab = r1.w;
            const float exbc = r2.x, eybc = r2.y;
            const float exca = r2.z, eyca = r2.w;
            // rect axes: triangle bbox vs tile rect (v_min3/v_max3)
            const float xmn = fminf(xa, fminf(xb, xc));
            const float xmx = fmaxf(xa, fmaxf(xb, xc));
            const float ymn = fminf(ya, fminf(yb, yc));
            const float ymx = fmaxf(ya, fmaxf(yb, yc));
            const bool bbok = (xmn <= rx1m) & (xmx >= rx0m) &
                              (ymn <= ry1m) & (ymx >= ry0m);
            // edge axes: affine cross -> F(center) +/- (|ex|+|ey|)*h
            #define EDGE_CR(ex, ey, vx, vy, Fc, rr)                           \
                const float Fc = (ex) * (cy - (vy)) - (ey) * (cx - (vx));     \
                const float rr = (fabsf(ex) + fabsf(ey)) * h;
            EDGE_CR(exab, eyab, xa, ya, FcAB, rAB)
            EDGE_CR(exbc, eybc, xb, yb, FcBC, rBC)
            EDGE_CR(exca, eyca, xc, yc, FcCA, rCA)
            #undef EDGE_CR
            const bool fwdPossible = (FcAB + rAB > -MARGIN) &
                                     (FcBC + rBC > -MARGIN) &
                                     (FcCA + rCA > -MARGIN);
            const bool revPossible = (FcAB - rAB <  MARGIN) &
                                     (FcBC - rBC <  MARGIN) &
                                     (FcCA - rCA <  MARGIN);
            keep = bbok & (fwdPossible | revPossible);
        }

        // ---- ballot + LDS compaction ----
        const unsigned long long m = __ballot((int)keep);
        const int cnt = __popcll(m);
        if (keep) {
            const int slot = __popcll(m & ((1ull << tid) - 1));
            fd[slot][0] = r0;
            fd[slot][1] = r1;
            fd[slot][2] = r2;
        }
        __syncthreads();

        // ---- serial exact test over compacted survivors (LDS broadcast) ----
        for (int i = 0; i < cnt; ++i) {
            const float4 A  = fd[i][0];
            const float4 Bv = fd[i][1];
            const float4 C  = fd[i][2];
            const float dxa = __fsub_rn(px, A.x),  dya = __fsub_rn(py, A.y);
            const float dxb = __fsub_rn(px, A.z),  dyb = __fsub_rn(py, A.w);
            const float dxc = __fsub_rn(px, Bv.x), dyc = __fsub_rn(py, Bv.y);
            const float exab = Bv.z, eyab = Bv.w;
            const float exbc = C.x,  eybc = C.y;
            const float exca = C.z,  eyca = C.w;
            const float F0 = __fsub_rn(__fmul_rn(exab, dya), __fmul_rn(eyab, dxa));
            const float F1 = __fsub_rn(__fmul_rn(exbc, dyb), __fmul_rn(eybc, dxb));
            const float F2 = __fsub_rn(__fmul_rn(exca, dyc), __fmul_rn(eyca, dxc));
            const float R0 = __fsub_rn(__fmul_rn(eybc, dxc), __fmul_rn(exbc, dyc));
            const float R1 = __fsub_rn(__fmul_rn(eyab, dxb), __fmul_rn(exab, dyb));
            const float R2 = __fsub_rn(__fmul_rn(eyca, dxa), __fmul_rn(exca, dya));
            const bool fwd = (F0 > 0.0f) & (F1 > 0.0f) & (F2 > 0.0f);
            const bool rev = (R0 > 0.0f) & (R1 > 0.0f) & (R2 > 0.0f);
            covered = covered || fwd || rev;
            if (__all((int)covered)) break;
        }

        const bool done = __all((int)covered);   // wave-uniform
        __syncthreads();                          // protect fd for next chunk
        if (done) break;
        r0 = n0; r1 = n1; r2 = n2;               // rotate double buffer
    }

    // vertical flip + 2x2 mean: quad lanes {t, t^1, t^8, t^9}
    float c = covered ? 1.0f : 0.0f;
    c += __shfl_xor(c, 1);
    c += __shfl_xor(c, 8);
    if (((tx & 1) == 0) && ((ty & 1) == 0)) {
        const int X = sx >> 1;
        const int Y = (OUTSZ - 1) - (sy >> 1);   // vertical flip
        out[((size_t)b * OUTSZ + Y) * OUTSZ + X] = c * 0.25f;
    }
}

extern "C" void kernel_launch(void* const* d_in, const int* in_sizes, int n_in,
                              void* d_out, int out_size, void* d_ws, size_t ws_size,
                              hipStream_t stream) {
    const float* verts = (const float*)d_in[0];
    const int*   faces = (const int*)d_in[1];
    float*       out   = (float*)d_out;

    const int B     = in_sizes[0] / (NVERT * 2);   // = 4
    const int total = B * NFACE;

    float4* recs = (float4*)d_ws;                  // [3][B*NFACE] SoA planes

    face_setup<<<(total + 255) / 256, 256, 0, stream>>>(verts, faces, recs, total);

    dim3 grid(S / 8, S / 8, B);
    raster8<<<grid, dim3(64), 0, stream>>>(recs, out, total);
}

// Round 6
// 19.615 us; speedup vs baseline: 13.1008x; 1.2265x over previous
//
#include <hip/hip_runtime.h>

// Rasterize_52321291600271 — round 6 (single fused kernel, 4-wave tiles)
// B=4, NV=1024, NF=1024, RASTER S=256, output 4x128x128 float32.
//
// One 256-thread block per 8x8-subpixel tile; all 4 waves map their 64
// lanes to the SAME 64 subpixels, each wave scans 4 of the 16 64-face
// chunks. Per chunk (NO __syncthreads in the loop):
//   - per-lane face-index load (next chunk prefetched in registers)
//   - vertex gather from an 8KB LDS copy of the batch's vertices
//   - in-lane edge vectors (bit-exact: IEEE f32 sub, same as reference)
//   - conservative SAT cull (bbox + center+radius edge extrema,
//     MARGIN 1e-4 >> ~1e-6 FP error)
//   - ballot + per-wave LDS compaction (wave-level lgkmcnt fence only)
//   - serial exact 6-cross test (__fmul_rn/__fsub_rn, no FMA — byte-
//     identical to the passing round-5 kernel)
//   - coverage union across waves via 64-bit LDS atomicOr; all waves
//     early-exit when the union is full (monotone, barrier-free)
// Epilogue: union mask -> vertical flip + 2x2 mean, written by wave 0.

constexpr int S     = 256;
constexpr int NVERT = 1024;
constexpr int NFACE = 1024;
constexpr int OUTSZ = 128;

__global__ __launch_bounds__(256)
void raster_fused(const float* __restrict__ verts,
                  const int*   __restrict__ faces,
                  float*       __restrict__ out)
{
    __shared__ float2 vlds[NVERT];                 // 8 KB vertex copy
    __shared__ float4 fd[4][64][3];                // 12 KB per-wave compaction
    __shared__ unsigned long long covMask;         // coverage union

    const int b    = blockIdx.z;
    const int tid  = threadIdx.x;
    const int lane = tid & 63;
    const int wid  = tid >> 6;
    const int tx   = lane & 7;
    const int ty   = lane >> 3;
    const int bx   = (int)(blockIdx.x << 3);       // signed tile origin
    const int by   = (int)(blockIdx.y << 3);
    const int sx   = bx + tx;
    const int sy   = by + ty;

    // (2j+1-S)/S exactly representable
    const float px  = (float)(2 * sx + 1 - S)       * (1.0f / (float)S);
    const float py  = (float)(2 * sy + 1 - S)       * (1.0f / (float)S);
    const float rx0 = (float)(2 * bx + 1 - S)       * (1.0f / (float)S);
    const float rx1 = (float)(2 * (bx + 7) + 1 - S) * (1.0f / (float)S);
    const float ry0 = (float)(2 * by + 1 - S)       * (1.0f / (float)S);
    const float ry1 = (float)(2 * (by + 7) + 1 - S) * (1.0f / (float)S);
    constexpr float MARGIN = 1e-4f;
    const float cx = (rx0 + rx1) * 0.5f;
    const float cy = (ry0 + ry1) * 0.5f;
    const float h  = (rx1 - rx0) * 0.5f;
    const float rx0m = rx0 - MARGIN, rx1m = rx1 + MARGIN;
    const float ry0m = ry0 - MARGIN, ry1m = ry1 + MARGIN;

    // ---- stage batch vertices into LDS (bit-exact copy), init mask ----
    {
        const float4* __restrict__ v4 = (const float4*)(verts + (size_t)b * NVERT * 2);
        float4* __restrict__ l4 = (float4*)vlds;
        #pragma unroll
        for (int i = 0; i < NVERT / 2 / 256; ++i)   // 512 float4 / 256 thr = 2
            l4[tid + i * 256] = v4[tid + i * 256];
    }
    if (tid == 0) covMask = 0ull;
    __syncthreads();

    const int* __restrict__ fb = faces + (size_t)b * NFACE * 3;

    bool covered = false;

    int c0 = wid * 64;
    int i0 = fb[3 * (c0 + lane) + 0];
    int i1 = fb[3 * (c0 + lane) + 1];
    int i2 = fb[3 * (c0 + lane) + 2];

    for (; c0 < NFACE; c0 += 256) {
        // ---- prefetch next chunk's indices (wave-uniform guard) ----
        const int nc = c0 + 256;
        int n0 = 0, n1 = 0, n2 = 0;
        if (nc < NFACE) {
            n0 = fb[3 * (nc + lane) + 0];
            n1 = fb[3 * (nc + lane) + 1];
            n2 = fb[3 * (nc + lane) + 2];
        }

        // ---- LDS vertex gather + in-lane edge vectors ----
        const float2 va = vlds[i0], vbb = vlds[i1], vcc = vlds[i2];
        const float xa = va.x,  ya = va.y;
        const float xb = vbb.x, yb = vbb.y;
        const float xc = vcc.x, yc = vcc.y;
        const float exab = __fsub_rn(xb, xa), eyab = __fsub_rn(yb, ya);
        const float exbc = __fsub_rn(xc, xb), eybc = __fsub_rn(yc, yb);
        const float exca = __fsub_rn(xa, xc), eyca = __fsub_rn(ya, yc);

        // ---- conservative SAT cull ----
        bool keep;
        {
            const float xmn = fminf(xa, fminf(xb, xc));
            const float xmx = fmaxf(xa, fmaxf(xb, xc));
            const float ymn = fminf(ya, fminf(yb, yc));
            const float ymx = fmaxf(ya, fmaxf(yb, yc));
            const bool bbok = (xmn <= rx1m) & (xmx >= rx0m) &
                              (ymn <= ry1m) & (ymx >= ry0m);
            #define EDGE_CR(ex, ey, vx, vy, Fc, rr)                           \
                const float Fc = (ex) * (cy - (vy)) - (ey) * (cx - (vx));     \
                const float rr = (fabsf(ex) + fabsf(ey)) * h;
            EDGE_CR(exab, eyab, xa, ya, FcAB, rAB)
            EDGE_CR(exbc, eybc, xb, yb, FcBC, rBC)
            EDGE_CR(exca, eyca, xc, yc, FcCA, rCA)
            #undef EDGE_CR
            const bool fwdP = (FcAB + rAB > -MARGIN) & (FcBC + rBC > -MARGIN) &
                              (FcCA + rCA > -MARGIN);
            const bool revP = (FcAB - rAB <  MARGIN) & (FcBC - rBC <  MARGIN) &
                              (FcCA - rCA <  MARGIN);
            keep = bbok & (fwdP | revP);
        }

        // ---- ballot + per-wave LDS compaction (no block barrier) ----
        const unsigned long long m = __ballot((int)keep);
        const int cnt = __popcll(m);
        asm volatile("s_waitcnt lgkmcnt(0)" ::: "memory");  // prior reads done
        if (keep) {
            const int slot = __popcll(m & ((1ull << lane) - 1));
            fd[wid][slot][0] = make_float4(xa, ya, xb, yb);
            fd[wid][slot][1] = make_float4(xc, yc, exab, eyab);
            fd[wid][slot][2] = make_float4(exbc, eybc, exca, eyca);
        }
        asm volatile("s_waitcnt lgkmcnt(0)" ::: "memory");  // writes visible to wave

        // ---- serial exact test over compacted survivors ----
        for (int i = 0; i < cnt; ++i) {
            const float4 A  = fd[wid][i][0];
            const float4 Bv = fd[wid][i][1];
            const float4 C  = fd[wid][i][2];
            const float dxa = __fsub_rn(px, A.x),  dya = __fsub_rn(py, A.y);
            const float dxb = __fsub_rn(px, A.z),  dyb = __fsub_rn(py, A.w);
            const float dxc = __fsub_rn(px, Bv.x), dyc = __fsub_rn(py, Bv.y);
            const float e0x = Bv.z, e0y = Bv.w;
            const float e1x = C.x,  e1y = C.y;
            const float e2x = C.z,  e2y = C.w;
            const float F0 = __fsub_rn(__fmul_rn(e0x, dya), __fmul_rn(e0y, dxa));
            const float F1 = __fsub_rn(__fmul_rn(e1x, dyb), __fmul_rn(e1y, dxb));
            const float F2 = __fsub_rn(__fmul_rn(e2x, dyc), __fmul_rn(e2y, dxc));
            const float R0 = __fsub_rn(__fmul_rn(e1y, dxc), __fmul_rn(e1x, dyc));
            const float R1 = __fsub_rn(__fmul_rn(e0y, dxb), __fmul_rn(e0x, dyb));
            const float R2 = __fsub_rn(__fmul_rn(e2y, dxa), __fmul_rn(e2x, dya));
            const bool fwd = (F0 > 0.0f) & (F1 > 0.0f) & (F2 > 0.0f);
            const bool rev = (R0 > 0.0f) & (R1 > 0.0f) & (R2 > 0.0f);
            covered = covered || fwd || rev;
            if (__all((int)covered)) break;
        }

        // ---- merge this wave's coverage into the block union ----
        const unsigned long long m2 = __ballot((int)covered);
        unsigned long long u = 0ull;
        if (lane == 0) u = atomicOr(&covMask, m2) | m2;
        u = __shfl(u, 0);
        if (u == ~0ull) break;                      // union full: all waves exit

        i0 = n0; i1 = n1; i2 = n2;
    }

    __syncthreads();                                // all waves contributed

    // ---- epilogue: union mask -> flip + 2x2 mean (wave 0 only) ----
    if (tid < 64) {
        const unsigned long long u = covMask;
        if (((tx & 1) == 0) && ((ty & 1) == 0)) {
            const float c = (float)(((u >> lane) & 1ull) +
                                    ((u >> (lane ^ 1)) & 1ull) +
                                    ((u >> (lane ^ 8)) & 1ull) +
                                    ((u >> (lane ^ 9)) & 1ull));
            const int X = sx >> 1;
            const int Y = (OUTSZ - 1) - (sy >> 1);  // vertical flip
            out[((size_t)b * OUTSZ + Y) * OUTSZ + X] = c * 0.25f;
        }
    }
}

extern "C" void kernel_launch(void* const* d_in, const int* in_sizes, int n_in,
                              void* d_out, int out_size, void* d_ws, size_t ws_size,
                              hipStream_t stream) {
    const float* verts = (const float*)d_in[0];
    const int*   faces = (const int*)d_in[1];
    float*       out   = (float*)d_out;

    const int B = in_sizes[0] / (NVERT * 2);        // = 4
    dim3 grid(S / 8, S / 8, B);
    raster_fused<<<grid, dim3(256), 0, stream>>>(verts, faces, out);
}

// Round 7
// 19.547 us; speedup vs baseline: 13.1466x; 1.0035x over previous
//
#include <hip/hip_runtime.h>

// Rasterize_52321291600271 — round 7 (readlane broadcast, no LDS in hot loop)
// B=4, NV=1024, NF=1024, RASTER S=256, output 4x128x128 float32.
//
// One 256-thread block per 8x8-subpixel tile; 4 waves map their 64 lanes
// to the SAME 64 subpixels; wave w scans chunks {w, w+4, w+8, w+12}.
// Per 64-face chunk (no __syncthreads in the loop):
//   - per-lane face-index load (next chunk prefetched in registers)
//   - vertex gather from an 8KB LDS copy; in-lane edge vectors (bit-exact
//     IEEE f32 subs, as the reference)
//   - conservative SAT cull (bbox + center+radius edge extrema,
//     MARGIN 1e-4 >> ~1e-6 FP error)
//   - ballot; for each set bit f: broadcast the 12 face floats from lane f
//     via __builtin_amdgcn_readlane (register->scalar, no memory), run the
//     exact 6-cross test (__fmul_rn/__fsub_rn, no FMA — byte-identical to
//     the passing round-6 kernel); check __all(covered) every 4 faces
//   - coverage union across waves via 64-bit LDS atomicOr; all waves
//     early-exit when the union is full (monotone, barrier-free)
// Epilogue: union mask -> vertical flip + 2x2 mean, written by wave 0.

constexpr int S     = 256;
constexpr int NVERT = 1024;
constexpr int NFACE = 1024;
constexpr int OUTSZ = 128;

__global__ __launch_bounds__(256)
void raster_fused(const float* __restrict__ verts,
                  const int*   __restrict__ faces,
                  float*       __restrict__ out)
{
    __shared__ float2 vlds[NVERT];                 // 8 KB vertex copy
    __shared__ unsigned long long covMask;         // coverage union

    const int b    = blockIdx.z;
    const int tid  = threadIdx.x;
    const int lane = tid & 63;
    const int wid  = tid >> 6;
    const int tx   = lane & 7;
    const int ty   = lane >> 3;
    const int bx   = (int)(blockIdx.x << 3);       // signed tile origin
    const int by   = (int)(blockIdx.y << 3);
    const int sx   = bx + tx;
    const int sy   = by + ty;

    // (2j+1-S)/S exactly representable
    const float px  = (float)(2 * sx + 1 - S)       * (1.0f / (float)S);
    const float py  = (float)(2 * sy + 1 - S)       * (1.0f / (float)S);
    const float rx0 = (float)(2 * bx + 1 - S)       * (1.0f / (float)S);
    const float rx1 = (float)(2 * (bx + 7) + 1 - S) * (1.0f / (float)S);
    const float ry0 = (float)(2 * by + 1 - S)       * (1.0f / (float)S);
    const float ry1 = (float)(2 * (by + 7) + 1 - S) * (1.0f / (float)S);
    constexpr float MARGIN = 1e-4f;
    const float cx = (rx0 + rx1) * 0.5f;
    const float cy = (ry0 + ry1) * 0.5f;
    const float h  = (rx1 - rx0) * 0.5f;
    const float rx0m = rx0 - MARGIN, rx1m = rx1 + MARGIN;
    const float ry0m = ry0 - MARGIN, ry1m = ry1 + MARGIN;

    // ---- stage batch vertices into LDS (bit-exact copy), init mask ----
    {
        const float4* __restrict__ v4 = (const float4*)(verts + (size_t)b * NVERT * 2);
        float4* __restrict__ l4 = (float4*)vlds;
        #pragma unroll
        for (int i = 0; i < NVERT / 2 / 256; ++i)   // 512 float4 / 256 thr = 2
            l4[tid + i * 256] = v4[tid + i * 256];
    }
    if (tid == 0) covMask = 0ull;
    __syncthreads();

    const int* __restrict__ fb = faces + (size_t)b * NFACE * 3;

    bool covered = false;

    int c0 = wid * 64;
    int i0 = fb[3 * (c0 + lane) + 0];
    int i1 = fb[3 * (c0 + lane) + 1];
    int i2 = fb[3 * (c0 + lane) + 2];

    for (; c0 < NFACE; c0 += 256) {
        // ---- prefetch next chunk's indices (wave-uniform guard) ----
        const int nc = c0 + 256;
        int n0 = 0, n1 = 0, n2 = 0;
        if (nc < NFACE) {
            n0 = fb[3 * (nc + lane) + 0];
            n1 = fb[3 * (nc + lane) + 1];
            n2 = fb[3 * (nc + lane) + 2];
        }

        // ---- LDS vertex gather + in-lane edge vectors ----
        const float2 va = vlds[i0], vbb = vlds[i1], vcc = vlds[i2];
        const float xa = va.x,  ya = va.y;
        const float xb = vbb.x, yb = vbb.y;
        const float xc = vcc.x, yc = vcc.y;
        const float exab = __fsub_rn(xb, xa), eyab = __fsub_rn(yb, ya);
        const float exbc = __fsub_rn(xc, xb), eybc = __fsub_rn(yc, yb);
        const float exca = __fsub_rn(xa, xc), eyca = __fsub_rn(ya, yc);

        // ---- conservative SAT cull ----
        bool keep;
        {
            const float xmn = fminf(xa, fminf(xb, xc));
            const float xmx = fmaxf(xa, fmaxf(xb, xc));
            const float ymn = fminf(ya, fminf(yb, yc));
            const float ymx = fmaxf(ya, fmaxf(yb, yc));
            const bool bbok = (xmn <= rx1m) & (xmx >= rx0m) &
                              (ymn <= ry1m) & (ymx >= ry0m);
            #define EDGE_CR(ex, ey, vx, vy, Fc, rr)                           \
                const float Fc = (ex) * (cy - (vy)) - (ey) * (cx - (vx));     \
                const float rr = (fabsf(ex) + fabsf(ey)) * h;
            EDGE_CR(exab, eyab, xa, ya, FcAB, rAB)
            EDGE_CR(exbc, eybc, xb, yb, FcBC, rBC)
            EDGE_CR(exca, eyca, xc, yc, FcCA, rCA)
            #undef EDGE_CR
            const bool fwdP = (FcAB + rAB > -MARGIN) & (FcBC + rBC > -MARGIN) &
                              (FcCA + rCA > -MARGIN);
            const bool revP = (FcAB - rAB <  MARGIN) & (FcBC - rBC <  MARGIN) &
                              (FcCA - rCA <  MARGIN);
            keep = bbok & (fwdP | revP);
        }

        // ---- iterate survivors: register broadcast via readlane ----
        unsigned long long m = __ballot((int)keep);
        int nt = 0;
        #define RL(v) __int_as_float(__builtin_amdgcn_readlane(__float_as_int(v), f))
        while (m) {
            const int f = __ffsll(m) - 1;
            m &= m - 1;
            const float Xa = RL(xa), Ya = RL(ya);
            const float Xb = RL(xb), Yb = RL(yb);
            const float Xc = RL(xc), Yc = RL(yc);
            const float E0x = RL(exab), E0y = RL(eyab);
            const float E1x = RL(exbc), E1y = RL(eybc);
            const float E2x = RL(exca), E2y = RL(eyca);
            const float dxa = __fsub_rn(px, Xa), dya = __fsub_rn(py, Ya);
            const float dxb = __fsub_rn(px, Xb), dyb = __fsub_rn(py, Yb);
            const float dxc = __fsub_rn(px, Xc), dyc = __fsub_rn(py, Yc);
            const float F0 = __fsub_rn(__fmul_rn(E0x, dya), __fmul_rn(E0y, dxa));
            const float F1 = __fsub_rn(__fmul_rn(E1x, dyb), __fmul_rn(E1y, dxb));
            const float F2 = __fsub_rn(__fmul_rn(E2x, dyc), __fmul_rn(E2y, dxc));
            const float R0 = __fsub_rn(__fmul_rn(E1y, dxc), __fmul_rn(E1x, dyc));
            const float R1 = __fsub_rn(__fmul_rn(E0y, dxb), __fmul_rn(E0x, dyb));
            const float R2 = __fsub_rn(__fmul_rn(E2y, dxa), __fmul_rn(E2x, dya));
            const bool fwd = (F0 > 0.0f) & (F1 > 0.0f) & (F2 > 0.0f);
            const bool rev = (R0 > 0.0f) & (R1 > 0.0f) & (R2 > 0.0f);
            covered = covered || fwd || rev;
            if (((++nt) & 3) == 0 && __all((int)covered)) break;
        }
        #undef RL

        // ---- merge this wave's coverage into the block union ----
        const unsigned long long m2 = __ballot((int)covered);
        unsigned long long u = 0ull;
        if (lane == 0) u = atomicOr(&covMask, m2) | m2;
        u = __shfl(u, 0);
        if (u == ~0ull) break;                      // union full: all waves exit

        i0 = n0; i1 = n1; i2 = n2;
    }

    __syncthreads();                                // all waves contributed

    // ---- epilogue: union mask -> flip + 2x2 mean (wave 0 only) ----
    if (tid < 64) {
        const unsigned long long u = covMask;
        if (((tx & 1) == 0) && ((ty & 1) == 0)) {
            const float c = (float)(((u >> lane) & 1ull) +
                                    ((u >> (lane ^ 1)) & 1ull) +
                                    ((u >> (lane ^ 8)) & 1ull) +
                                    ((u >> (lane ^ 9)) & 1ull));
            const int X = sx >> 1;
            const int Y = (OUTSZ - 1) - (sy >> 1);  // vertical flip
            out[((size_t)b * OUTSZ + Y) * OUTSZ + X] = c * 0.25f;
        }
    }
}

extern "C" void kernel_launch(void* const* d_in, const int* in_sizes, int n_in,
                              void* d_out, int out_size, void* d_ws, size_t ws_size,
                              hipStream_t stream) {
    const float* verts = (const float*)d_in[0];
    const int*   faces = (const int*)d_in[1];
    float*       out   = (float*)d_out;

    const int B = in_sizes[0] / (NVERT * 2);        // = 4
    dim3 grid(S / 8, S / 8, B);
    raster_fused<<<grid, dim3(256), 0, stream>>>(verts, faces, out);
}